// Round 13
// baseline (119.696 us; speedup 1.0000x reference)
//
#include <hip/hip_runtime.h>
#include <hip/hip_bf16.h>
#include <stdint.h>

typedef __attribute__((ext_vector_type(8))) short bf16x8;
typedef __attribute__((ext_vector_type(4))) float f32x4;

#define NB 8192

__device__ __forceinline__ unsigned pkbf(float x, float y) {
    __hip_bfloat162 h = __float22bfloat162_rn(make_float2(x, y));  // v_cvt_pk_bf16_f32 (RNE)
    unsigned r;
    __builtin_memcpy(&r, &h, 4);
    return r;
}

__device__ __forceinline__ uint4 pack8(float4 a, float4 b) {
    uint4 r;
    r.x = pkbf(a.x, a.y);
    r.y = pkbf(a.z, a.w);
    r.z = pkbf(b.x, b.y);
    r.w = pkbf(b.z, b.w);
    return r;
}

__device__ __forceinline__ void gload16(const float* g, void* l) {
    __builtin_amdgcn_global_load_lds(
        (const __attribute__((address_space(1))) void*)g,
        (__attribute__((address_space(3))) void*)l, 16, 0, 0);
}

// ---------------------------------------------------------------------------
// prep_w: W[512][2048] fp32 -> bf16 fragment-linear (B operand). Unchanged.
// ---------------------------------------------------------------------------
__global__ __launch_bounds__(256)
void prep_w_kernel(const float* __restrict__ W, uint4* __restrict__ Wt) {
    int t = blockIdx.x * 256 + threadIdx.x;
    int lane = t & 63;
    int frag = t >> 6;
    int kb = frag >> 5, cb = frag & 31;
    int o = cb * 16 + (lane & 15);
    int k = kb * 32 + ((lane >> 4) << 3);
    const float* src = W + (size_t)o * 2048 + k;
    Wt[t] = pack8(*(const float4*)src, *(const float4*)(src + 4));
}

// ---------------------------------------------------------------------------
// score v14: 768 blocks x 512 thr (8 waves), node=bid%6, tile=bid/6, BM=64,
// BN=512 (wave w: cols [w*64,+64)), acc[4][4]=64 AGPR.
//
// Pipeline (FIFO-aware, fixes v13's crash + overlap flaw):
//  - DMA for buffer s+1 issued at buffer-s START (4 global_load_lds / wave,
//    WAVE-UNIFORM LDS dest: base + (w*4+i)*1024; HW adds lane*16).
//  - B fragments prefetched at kbh distance 2 in a period-4 static ring
//    (slot = kb&3: static under the unrolled kbh loop). All B consumed in
//    buffer s+1 is issued AFTER DMA(s+1) => its first vmcnt-counted wait
//    FIFO-drains the DMA. No vmcnt(0) in the k-loop: RAW s_barrier only.
//  - Read-safety: ds_read data is consumed by pre-barrier MFMAs (compiler
//    lgkmcnt), so in-registers before any wave crosses the barrier.
//
// LDS: 2 x 32KB fp32 buffers (64 rows x 128 k, 512B/row = 32 16B-slots).
// Swizzle phys_slot = logical ^ (row&7), applied on the per-lane GLOBAL
// source (DMA dest must be linear) and on ds_read addresses -> <=2-way.
// fp32->bf16 cvt on read (v_cvt_pk, 16 VALU per kbh << MFMA time).
// ---------------------------------------------------------------------------
template<int DN>
__device__ __forceinline__ void score_body(
        const float* __restrict__ xp, int node, int tile,
        const float* __restrict__ bias, const float* __restrict__ hvec,
        const uint4* __restrict__ Wt, float* __restrict__ scores,
        char* lds, float* red) {
    constexpr int NBUF = DN / 128;     // 8 heavy, 4 light
    constexpr int NKB = DN / 32;
    int t = threadIdx.x;
    int l = t & 63;
    int w = t >> 6;
    int m0 = tile << 6;

    // DMA staging geometry (instr i of wave w; lane l implicit):
    //   LDS dest (uniform) = buf + (w*4+i)*1024
    //   lane l -> row r = (w*4+i)*2 + (l>>5), phys slot sp = l&31
    //   global col group  = sp ^ (r&7)  (16B logical slot)
    int rA[4], gcol[4];
#pragma unroll
    for (int i = 0; i < 4; ++i) {
        int r = (((w << 2) + i) << 1) + (l >> 5);
        rA[i] = r;
        gcol[i] = ((l & 31) ^ (r & 7)) << 2;   // fp32 offset within 128-k slab
    }

    f32x4 acc[4][4];
#pragma unroll
    for (int mf = 0; mf < 4; ++mf)
#pragma unroll
        for (int nf = 0; nf < 4; ++nf)
            acc[mf][nf] = (f32x4){0.f, 0.f, 0.f, 0.f};

    // B ring: period 4, prefetch distance 2. slot(kb) = kb & 3 (static).
    uint4 bR[4][4];

    // ---- prologue: DMA buffer 0; preload B(0), B(1) ----
#pragma unroll
    for (int i = 0; i < 4; ++i)
        gload16(xp + (size_t)(m0 + rA[i]) * DN + gcol[i],
                lds + (((w << 2) + i) << 10));
#pragma unroll
    for (int pk = 0; pk < 2; ++pk) {
        const uint4* wp = Wt + (((pk << 5) + (w << 2)) << 6) + l;
#pragma unroll
        for (int nf = 0; nf < 4; ++nf) bR[pk][nf] = wp[nf << 6];
    }
    __syncthreads();                     // one-time full drain: buf0 ready

    for (int s = 0; s < NBUF; ++s) {
        int cur = s & 1;
        const char* buf = lds + (cur << 15);
        // DMA for buffer s+1 (lands during this buffer's compute; drained
        // by buffer s+1's first B-wait via FIFO)
        if (s + 1 < NBUF) {
            int koff = (s + 1) << 7;
#pragma unroll
            for (int i = 0; i < 4; ++i)
                gload16(xp + (size_t)(m0 + rA[i]) * DN + koff + gcol[i],
                        lds + ((cur ^ 1) << 15) + (((w << 2) + i) << 10));
        }
        __builtin_amdgcn_sched_barrier(0);   // pin: B prefetches stay after DMA
#pragma unroll
        for (int kbh = 0; kbh < 4; ++kbh) {
            int kb = (s << 2) + kbh;
            // prefetch B(kb+2) into static ring slot (kbh+2)&3
            if (kb + 2 < NKB) {
                const uint4* wp = Wt + ((((kb + 2) << 5) + (w << 2)) << 6) + l;
#pragma unroll
                for (int nf = 0; nf < 4; ++nf) bR[(kbh + 2) & 3][nf] = wp[nf << 6];
            }
            // A fragments: swizzled fp32 ds_read + cvt -> bf16, then MFMA
#pragma unroll
            for (int mf = 0; mf < 4; ++mf) {
                int r = (mf << 4) + (l & 15);
                int s0 = (kbh << 3) + ((l >> 4) << 1);
                int sw = r & 7;
                const char* p = buf + r * 512;
                float4 lo = *(const float4*)(p + ((s0 ^ sw) << 4));
                float4 hi = *(const float4*)(p + (((s0 + 1) ^ sw) << 4));
                uint4 pkd = pack8(lo, hi);
                bf16x8 afr;
                __builtin_memcpy(&afr, &pkd, 16);
#pragma unroll
                for (int nf = 0; nf < 4; ++nf) {
                    bf16x8 bfr;
                    __builtin_memcpy(&bfr, &bR[kbh & 3][nf], 16);
                    acc[mf][nf] = __builtin_amdgcn_mfma_f32_16x16x32_bf16(
                        afr, bfr, acc[mf][nf], 0, 0, 0);
                }
            }
        }
        // raw barrier: NO vmcnt drain (the point of the whole structure)
        __builtin_amdgcn_sched_barrier(0);
        __builtin_amdgcn_s_barrier();
        __builtin_amdgcn_sched_barrier(0);
    }

    // ---- epilogue: tanh, dot with h, reduce to per-row score ----
    float bv[4], hv[4];
#pragma unroll
    for (int nf = 0; nf < 4; ++nf) {
        int o = (w << 6) + (nf << 4) + (l & 15);
        bv[nf] = bias[o];
        hv[nf] = hvec[o];
    }
#pragma unroll
    for (int mf = 0; mf < 4; ++mf) {
        float sc[4] = {0.f, 0.f, 0.f, 0.f};
#pragma unroll
        for (int nf = 0; nf < 4; ++nf) {
#pragma unroll
            for (int r = 0; r < 4; ++r) {
                float xv = acc[mf][nf][r] + bv[nf];
                float th = 1.f - 2.f * __builtin_amdgcn_rcpf(1.f + __expf(2.f * xv));
                sc[r] = fmaf(hv[nf], th, sc[r]);
            }
        }
#pragma unroll
        for (int r = 0; r < 4; ++r) {
            float v = sc[r];
            v += __shfl_xor(v, 1);
            v += __shfl_xor(v, 2);
            v += __shfl_xor(v, 4);
            v += __shfl_xor(v, 8);
            if ((l & 15) == 0)
                red[(w << 6) + (mf << 4) + ((l >> 4) << 2) + r] = v;
        }
    }
    __syncthreads();
    if (t < 64) {
        float ssum = 0.f;
#pragma unroll
        for (int w2 = 0; w2 < 8; ++w2) ssum += red[(w2 << 6) + t];
        scores[node * NB + m0 + t] = ssum;
    }
}

__global__ __launch_bounds__(512)
void score_kernel(const float* __restrict__ x0, const float* __restrict__ x1,
                  const float* __restrict__ x2, const float* __restrict__ x3,
                  const float* __restrict__ x4, const float* __restrict__ x5,
                  const float* __restrict__ bias, const float* __restrict__ hvec,
                  const uint4* __restrict__ Wt, float* __restrict__ scores) {
    __shared__ char lds[65536];       // 2 x 32KB fp32 A buffers
    __shared__ float red[8 * 64];     // 2 KB
    int bid = blockIdx.x;
    int node = bid % 6;
    int tile = bid / 6;
    switch (node) {
        case 0: score_body<1024>(x0, 0, tile, bias, hvec, Wt, scores, lds, red); break;
        case 1: score_body<512>(x1, 1, tile, bias, hvec, Wt, scores, lds, red); break;
        case 2: score_body<512>(x2, 2, tile, bias, hvec, Wt, scores, lds, red); break;
        case 3: score_body<512>(x3, 3, tile, bias, hvec, Wt, scores, lds, red); break;
        case 4: score_body<1024>(x4, 4, tile, bias, hvec, Wt, scores, lds, red); break;
        default: score_body<512>(x5, 5, tile, bias, hvec, Wt, scores, lds, red); break;
    }
}

// ---------------------------------------------------------------------------
// z kernel: one wave per batch. softmax over 6 scores, then
// z[0:512]=sum beta_n x_n ; z[512:1024]=b0*ls+b4*ds ; z[1024:2048]=0
// ---------------------------------------------------------------------------
__global__ __launch_bounds__(256)
void z_kernel(const float* __restrict__ x0, const float* __restrict__ x1,
              const float* __restrict__ x2, const float* __restrict__ x3,
              const float* __restrict__ x4, const float* __restrict__ x5,
              const float* __restrict__ scores, float* __restrict__ out) {
    int wv = threadIdx.x >> 6;
    int lane = threadIdx.x & 63;
    int b = (blockIdx.x << 2) + wv;

    float s0 = scores[b];
    float s1 = scores[NB + b];
    float s2 = scores[2 * NB + b];
    float s3 = scores[3 * NB + b];
    float s4 = scores[4 * NB + b];
    float s5 = scores[5 * NB + b];
    float m = fmaxf(fmaxf(fmaxf(s0, s1), fmaxf(s2, s3)), fmaxf(s4, s5));
    float e0 = __expf(s0 - m), e1 = __expf(s1 - m), e2 = __expf(s2 - m);
    float e3 = __expf(s3 - m), e4 = __expf(s4 - m), e5 = __expf(s5 - m);
    float inv = __builtin_amdgcn_rcpf(e0 + e1 + e2 + e3 + e4 + e5);
    float b0 = e0 * inv, b1 = e1 * inv, b2 = e2 * inv;
    float b3 = e3 * inv, b4 = e4 * inv, b5 = e5 * inv;

    const float* pls = x0 + (size_t)b * 1024;
    const float* pA  = x1 + (size_t)b * 512;
    const float* plm = x2 + (size_t)b * 512;
    const float* pAT = x3 + (size_t)b * 512;
    const float* pds = x4 + (size_t)b * 1024;
    const float* pdm = x5 + (size_t)b * 512;
    float* po = out + (size_t)b * 2048;

#pragma unroll
    for (int j = 0; j < 2; ++j) {
        int c = (j << 8) + (lane << 2);
        float4 vls = *(const float4*)(pls + c);
        float4 vA  = *(const float4*)(pA + c);
        float4 vlm = *(const float4*)(plm + c);
        float4 vAT = *(const float4*)(pAT + c);
        float4 vds = *(const float4*)(pds + c);
        float4 vdm = *(const float4*)(pdm + c);
        float4 r;
        r.x = b0*vls.x + b1*vA.x + b2*vlm.x + b3*vAT.x + b4*vds.x + b5*vdm.x;
        r.y = b0*vls.y + b1*vA.y + b2*vlm.y + b3*vAT.y + b4*vds.y + b5*vdm.y;
        r.z = b0*vls.z + b1*vA.z + b2*vlm.z + b3*vAT.z + b4*vds.z + b5*vdm.z;
        r.w = b0*vls.w + b1*vA.w + b2*vlm.w + b3*vAT.w + b4*vds.w + b5*vdm.w;
        *(float4*)(po + c) = r;
    }
#pragma unroll
    for (int j = 0; j < 2; ++j) {
        int c = 512 + (j << 8) + (lane << 2);
        float4 vls = *(const float4*)(pls + c);
        float4 vds = *(const float4*)(pds + c);
        float4 r;
        r.x = b0*vls.x + b4*vds.x;
        r.y = b0*vls.y + b4*vds.y;
        r.z = b0*vls.z + b4*vds.z;
        r.w = b0*vls.w + b4*vds.w;
        *(float4*)(po + c) = r;
    }
    float4 zz = make_float4(0.f, 0.f, 0.f, 0.f);
#pragma unroll
    for (int j = 0; j < 4; ++j) {
        int c = 1024 + (j << 8) + (lane << 2);
        *(float4*)(po + c) = zz;
    }
}

extern "C" void kernel_launch(void* const* d_in, const int* in_sizes, int n_in,
                              void* d_out, int out_size, void* d_ws, size_t ws_size,
                              hipStream_t stream) {
    const float* x0   = (const float*)d_in[0];  // ls  [8192,1024]
    const float* x1   = (const float*)d_in[1];  // A   [8192,512]
    const float* x2   = (const float*)d_in[2];  // lm  [8192,512]
    const float* x3   = (const float*)d_in[3];  // AT  [8192,512]
    const float* x4   = (const float*)d_in[4];  // ds  [8192,1024]
    const float* x5   = (const float*)d_in[5];  // dm  [8192,512]
    const float* W    = (const float*)d_in[6];  // [512,2048]
    const float* bias = (const float*)d_in[7];  // [512]
    const float* hvec = (const float*)d_in[8];  // [512,1]

    uint4* Wt = (uint4*)d_ws;                              // 1 MB
    float* scores = (float*)((char*)d_ws + (1u << 20));    // 192 KB

    prep_w_kernel<<<256, 256, 0, stream>>>(W, Wt);
    score_kernel<<<768, 512, 0, stream>>>(x0, x1, x2, x3, x4, x5, bias, hvec, Wt, scores);
    z_kernel<<<2048, 256, 0, stream>>>(x0, x1, x2, x3, x4, x5, scores, (float*)d_out);
}

// Round 14
// 111.386 us; speedup vs baseline: 1.0746x; 1.0746x over previous
//
#include <hip/hip_runtime.h>
#include <hip/hip_bf16.h>
#include <stdint.h>

typedef __attribute__((ext_vector_type(8))) short bf16x8;
typedef __attribute__((ext_vector_type(4))) float f32x4;

#define NB 8192

__device__ __forceinline__ unsigned pkbf(float x, float y) {
    __hip_bfloat162 h = __float22bfloat162_rn(make_float2(x, y));  // v_cvt_pk_bf16_f32 (RNE)
    unsigned r;
    __builtin_memcpy(&r, &h, 4);
    return r;
}

__device__ __forceinline__ uint4 pack8(float4 a, float4 b) {
    uint4 r;
    r.x = pkbf(a.x, a.y);
    r.y = pkbf(a.z, a.w);
    r.z = pkbf(b.x, b.y);
    r.w = pkbf(b.z, b.w);
    return r;
}

__device__ __forceinline__ void gload16(const float* g, void* l) {
    __builtin_amdgcn_global_load_lds(
        (const __attribute__((address_space(1))) void*)g,
        (__attribute__((address_space(3))) void*)l, 16, 0, 0);
}

// ---------------------------------------------------------------------------
// prep_w: W[512][2048] fp32 -> bf16 fragment-linear (B operand). Unchanged.
// Fragment (kb,cb): uint4 index (kb*32+cb)*64 + lane;
// elem j = W[cb*16 + (lane&15)][kb*32 + (lane>>4)*8 + j]
// ---------------------------------------------------------------------------
__global__ __launch_bounds__(256)
void prep_w_kernel(const float* __restrict__ W, uint4* __restrict__ Wt) {
    int t = blockIdx.x * 256 + threadIdx.x;
    int lane = t & 63;
    int frag = t >> 6;
    int kb = frag >> 5, cb = frag & 31;
    int o = cb * 16 + (lane & 15);
    int k = kb * 32 + ((lane >> 4) << 3);
    const float* src = W + (size_t)o * 2048 + k;
    Wt[t] = pack8(*(const float4*)src, *(const float4*)(src + 4));
}

// ---------------------------------------------------------------------------
// score v15: 384 blocks x 1024 thr (16 waves = 4 waves/SIMD -- first real
// TLP increase; rounds 1-14 all ran <=2 useful waves/SIMD and every memory
// stall was exposed). BM=128, wave tile 32x128: wave w -> rg=w>>2 (rows
// [rg*32,+32)), cg=w&3 (cols [cg*128,+128)), acc[2][8] = 64 AGPR.
// Non-redundant B split -> B L2 traffic halves to 256 MB total.
//
// A: global_load_lds direct from fp32 x (wave-uniform LDS dest = buf +
// (w*4+i)*1024; HW adds lane*16). 2 x 64KB buffers (128 rows x 128 k fp32,
// 512B/row = 32 16B slots), DMA for buffer s+1 issued at buffer-s start ->
// in flight across full compute phase; the __syncthreads drain is then
// throughput-matched to the A HBM stream (~20us aggregate floor).
// Swizzle: phys_slot = logical ^ (row&7) applied on per-lane GLOBAL source
// and on ds_read -> <=2-way (free, m136). fp32->bf16 cvt on read: 8 cvt_pk
// per wave-kbh = 64 VALU-cyc/SIMD vs 307 MFMA-cyc/SIMD -- hidden.
// Heavy (DN=1024) blocks dispatched first (long-pole-first).
// ---------------------------------------------------------------------------
template<int DN>
__device__ __forceinline__ void score_body(
        const float* __restrict__ xp, int node, int tile,
        const float* __restrict__ bias, const float* __restrict__ hvec,
        const uint4* __restrict__ Wt, float* __restrict__ scores,
        char* lds, float* red) {
    constexpr int NBUF = DN / 128;     // 8 heavy, 4 light
    int t = threadIdx.x;
    int l = t & 63;
    int w = t >> 6;                    // 0..15
    int rg = w >> 2;                   // row group: rows [rg*32, +32)
    int cg = w & 3;                    // col group: cols [cg*128, +128)
    int m0 = tile << 7;                // BM=128

    // DMA geometry: instr j = w*4+i covers rows j*2,(j*2+1); lane l ->
    // row r = j*2 + (l>>5), phys slot = l&31, global col = (phys^(r&7)).
    int rL[4], gc[4];
#pragma unroll
    for (int i = 0; i < 4; ++i) {
        int j = (w << 2) + i;
        int r = (j << 1) + (l >> 5);
        rL[4 - 4 + i] = r;
        gc[i] = ((l & 31) ^ (r & 7)) << 2;   // fp32 offset within 128-k slab
    }

    f32x4 acc[2][8];
#pragma unroll
    for (int mf = 0; mf < 2; ++mf)
#pragma unroll
        for (int nf = 0; nf < 8; ++nf)
            acc[mf][nf] = (f32x4){0.f, 0.f, 0.f, 0.f};

    // prologue: DMA buffer 0
#pragma unroll
    for (int i = 0; i < 4; ++i)
        gload16(xp + (size_t)(m0 + rL[i]) * DN + gc[i],
                lds + ((((w << 2) + i)) << 10));
    __syncthreads();

    for (int s = 0; s < NBUF; ++s) {
        int cur = s & 1;
        const char* buf = lds + (cur << 16);
        // DMA buffer s+1 (in flight across this buffer's compute)
        if (s + 1 < NBUF) {
            int koff = (s + 1) << 7;
#pragma unroll
            for (int i = 0; i < 4; ++i)
                gload16(xp + (size_t)(m0 + rL[i]) * DN + koff + gc[i],
                        lds + ((cur ^ 1) << 16) + ((((w << 2) + i)) << 10));
        }
        // compute 4 kbh of this buffer
#pragma unroll
        for (int kbh = 0; kbh < 4; ++kbh) {
            int kb = (s << 2) + kbh;
            // B fragments (L2-hot, fragment-linear): cb = cg*8 + nf
            bf16x8 bfr[8];
#pragma unroll
            for (int nf = 0; nf < 8; ++nf) {
                uint4 u = Wt[(((kb << 5) + (cg << 3) + nf) << 6) + l];
                __builtin_memcpy(&bfr[nf], &u, 16);
            }
            // A fragments: swizzled fp32 ds_read + cvt -> bf16
#pragma unroll
            for (int mf = 0; mf < 2; ++mf) {
                int r = (rg << 5) + (mf << 4) + (l & 15);
                int s0 = (kbh << 3) + ((l >> 4) << 1);
                int sw = r & 7;
                const char* p = buf + r * 512;
                float4 lo = *(const float4*)(p + ((s0 ^ sw) << 4));
                float4 hi = *(const float4*)(p + (((s0 + 1) ^ sw) << 4));
                uint4 pk = pack8(lo, hi);
                bf16x8 afr;
                __builtin_memcpy(&afr, &pk, 16);
#pragma unroll
                for (int nf = 0; nf < 8; ++nf)
                    acc[mf][nf] = __builtin_amdgcn_mfma_f32_16x16x32_bf16(
                        afr, bfr[nf], acc[mf][nf], 0, 0, 0);
            }
        }
        __syncthreads();   // drains next DMA (landed during compute) + safety
    }

    // epilogue: tanh, dot with h, reduce to per-row score
    float bv[8], hv[8];
#pragma unroll
    for (int nf = 0; nf < 8; ++nf) {
        int o = (cg << 7) + (nf << 4) + (l & 15);
        bv[nf] = bias[o];
        hv[nf] = hvec[o];
    }
#pragma unroll
    for (int mf = 0; mf < 2; ++mf) {
        float sc[4] = {0.f, 0.f, 0.f, 0.f};
#pragma unroll
        for (int nf = 0; nf < 8; ++nf) {
#pragma unroll
            for (int r = 0; r < 4; ++r) {
                float xv = acc[mf][nf][r] + bv[nf];
                float th = 1.f - 2.f * __builtin_amdgcn_rcpf(1.f + __expf(2.f * xv));
                sc[r] = fmaf(hv[nf], th, sc[r]);
            }
        }
#pragma unroll
        for (int r = 0; r < 4; ++r) {
            float v = sc[r];
            v += __shfl_xor(v, 1);
            v += __shfl_xor(v, 2);
            v += __shfl_xor(v, 4);
            v += __shfl_xor(v, 8);
            if ((l & 15) == 0)
                red[(w << 5) + (mf << 4) + ((l >> 4) << 2) + r] = v;
        }
    }
    __syncthreads();
    if (t < 128) {
        int rg2 = t >> 5, lr = t & 31;
        float ssum = 0.f;
#pragma unroll
        for (int cg2 = 0; cg2 < 4; ++cg2)
            ssum += red[(((rg2 << 2) + cg2) << 5) + lr];
        scores[node * NB + m0 + t] = ssum;
    }
}

__global__ __launch_bounds__(1024, 4)
void score_kernel(const float* __restrict__ x0, const float* __restrict__ x1,
                  const float* __restrict__ x2, const float* __restrict__ x3,
                  const float* __restrict__ x4, const float* __restrict__ x5,
                  const float* __restrict__ bias, const float* __restrict__ hvec,
                  const uint4* __restrict__ Wt, float* __restrict__ scores) {
    __shared__ char lds[131072];      // 2 x 64KB fp32 A buffers
    __shared__ float red[16 * 32];    // 2 KB
    int bid = blockIdx.x;
    if (bid < 128) {
        // heavy nodes first (long pole): node 0 for bid<64, node 4 after
        int node = (bid < 64) ? 0 : 4;
        const float* xp = (bid < 64) ? x0 : x4;
        int tile = bid & 63;
        score_body<1024>(xp, node, tile, bias, hvec, Wt, scores, lds, red);
    } else {
        int lb = bid - 128;
        int ni = lb & 3;               // 0..3 -> nodes 1,2,3,5
        const float* xp = (ni == 0) ? x1 : (ni == 1) ? x2 : (ni == 2) ? x3 : x5;
        int node = (ni == 0) ? 1 : (ni == 1) ? 2 : (ni == 2) ? 3 : 5;
        int tile = lb >> 2;
        score_body<512>(xp, node, tile, bias, hvec, Wt, scores, lds, red);
    }
}

// ---------------------------------------------------------------------------
// z kernel: one wave per batch. softmax over 6 scores, then
// z[0:512]=sum beta_n x_n ; z[512:1024]=b0*ls+b4*ds ; z[1024:2048]=0
// ---------------------------------------------------------------------------
__global__ __launch_bounds__(256)
void z_kernel(const float* __restrict__ x0, const float* __restrict__ x1,
              const float* __restrict__ x2, const float* __restrict__ x3,
              const float* __restrict__ x4, const float* __restrict__ x5,
              const float* __restrict__ scores, float* __restrict__ out) {
    int wv = threadIdx.x >> 6;
    int lane = threadIdx.x & 63;
    int b = (blockIdx.x << 2) + wv;

    float s0 = scores[b];
    float s1 = scores[NB + b];
    float s2 = scores[2 * NB + b];
    float s3 = scores[3 * NB + b];
    float s4 = scores[4 * NB + b];
    float s5 = scores[5 * NB + b];
    float m = fmaxf(fmaxf(fmaxf(s0, s1), fmaxf(s2, s3)), fmaxf(s4, s5));
    float e0 = __expf(s0 - m), e1 = __expf(s1 - m), e2 = __expf(s2 - m);
    float e3 = __expf(s3 - m), e4 = __expf(s4 - m), e5 = __expf(s5 - m);
    float inv = __builtin_amdgcn_rcpf(e0 + e1 + e2 + e3 + e4 + e5);
    float b0 = e0 * inv, b1 = e1 * inv, b2 = e2 * inv;
    float b3 = e3 * inv, b4 = e4 * inv, b5 = e5 * inv;

    const float* pls = x0 + (size_t)b * 1024;
    const float* pA  = x1 + (size_t)b * 512;
    const float* plm = x2 + (size_t)b * 512;
    const float* pAT = x3 + (size_t)b * 512;
    const float* pds = x4 + (size_t)b * 1024;
    const float* pdm = x5 + (size_t)b * 512;
    float* po = out + (size_t)b * 2048;

#pragma unroll
    for (int j = 0; j < 2; ++j) {
        int c = (j << 8) + (lane << 2);
        float4 vls = *(const float4*)(pls + c);
        float4 vA  = *(const float4*)(pA + c);
        float4 vlm = *(const float4*)(plm + c);
        float4 vAT = *(const float4*)(pAT + c);
        float4 vds = *(const float4*)(pds + c);
        float4 vdm = *(const float4*)(pdm + c);
        float4 r;
        r.x = b0*vls.x + b1*vA.x + b2*vlm.x + b3*vAT.x + b4*vds.x + b5*vdm.x;
        r.y = b0*vls.y + b1*vA.y + b2*vlm.y + b3*vAT.y + b4*vds.y + b5*vdm.y;
        r.z = b0*vls.z + b1*vA.z + b2*vlm.z + b3*vAT.z + b4*vds.z + b5*vdm.z;
        r.w = b0*vls.w + b1*vA.w + b2*vlm.w + b3*vAT.w + b4*vds.w + b5*vdm.w;
        *(float4*)(po + c) = r;
    }
#pragma unroll
    for (int j = 0; j < 2; ++j) {
        int c = 512 + (j << 8) + (lane << 2);
        float4 vls = *(const float4*)(pls + c);
        float4 vds = *(const float4*)(pds + c);
        float4 r;
        r.x = b0*vls.x + b4*vds.x;
        r.y = b0*vls.y + b4*vds.y;
        r.z = b0*vls.z + b4*vds.z;
        r.w = b0*vls.w + b4*vds.w;
        *(float4*)(po + c) = r;
    }
    float4 zz = make_float4(0.f, 0.f, 0.f, 0.f);
#pragma unroll
    for (int j = 0; j < 4; ++j) {
        int c = 1024 + (j << 8) + (lane << 2);
        *(float4*)(po + c) = zz;
    }
}

extern "C" void kernel_launch(void* const* d_in, const int* in_sizes, int n_in,
                              void* d_out, int out_size, void* d_ws, size_t ws_size,
                              hipStream_t stream) {
    const float* x0   = (const float*)d_in[0];  // ls  [8192,1024]
    const float* x1   = (const float*)d_in[1];  // A   [8192,512]
    const float* x2   = (const float*)d_in[2];  // lm  [8192,512]
    const float* x3   = (const float*)d_in[3];  // AT  [8192,512]
    const float* x4   = (const float*)d_in[4];  // ds  [8192,1024]
    const float* x5   = (const float*)d_in[5];  // dm  [8192,512]
    const float* W    = (const float*)d_in[6];  // [512,2048]
    const float* bias = (const float*)d_in[7];  // [512]
    const float* hvec = (const float*)d_in[8];  // [512,1]

    uint4* Wt = (uint4*)d_ws;                              // 1 MB
    float* scores = (float*)((char*)d_ws + (1u << 20));    // 192 KB

    prep_w_kernel<<<256, 256, 0, stream>>>(W, Wt);
    score_kernel<<<384, 1024, 0, stream>>>(x0, x1, x2, x3, x4, x5, bias, hvec, Wt, scores);
    z_kernel<<<2048, 256, 0, stream>>>(x0, x1, x2, x3, x4, x5, scores, (float*)d_out);
}